// Round 2
// baseline (677.000 us; speedup 1.0000x reference)
//
#include <hip/hip_runtime.h>
#include <cstdint>
#include <cstddef>

// ConfusionDropout: B=16384 rows; D=4096 channels; C=1000 classes; drop top 25% (1024).
// One WAVE per row: all reductions are wave-internal (ballot/shfl), zero barriers, zero LDS.
constexpr int Dn    = 4096;
constexpr int Cn    = 1000;
constexpr int NDROP = 1024;          // Dn * 0.25
constexpr int TPB   = 256;           // 4 independent waves (rows) per block

// Monotonic (value, smaller-index-wins) packing matching lax.top_k tie-break.
__device__ __forceinline__ unsigned long long pack_pv(float v, unsigned idx) {
  unsigned b = __float_as_uint(v);
  unsigned u = b ^ ((b & 0x80000000u) ? 0xFFFFFFFFu : 0x80000000u);
  return ((unsigned long long)u << 32) | (unsigned)(~idx);
}

__global__ __launch_bounds__(TPB) void ConfusionDropout_52407190946399_kernel(
    const float* __restrict__ x,
    const float* __restrict__ prev,
    const float* __restrict__ W,
    float* __restrict__ out)
{
  const int wave = threadIdx.x >> 6;
  const int l    = threadIdx.x & 63;
  const int row  = blockIdx.x * (TPB / 64) + wave;
  const unsigned long long ltmask = (1ull << l) - 1ull;   // lanes strictly below me

  // ---------------- Phase A: top-2 of prev[row, :] (wave-internal) ----------------
  unsigned long long a0 = 0ull, a1 = 0ull;
  {
    const float* pr = prev + (size_t)row * Cn;
    #pragma unroll
    for (int k = 0; k < 16; ++k) {
      int c = l + k * 64;
      if (c < Cn) {
        unsigned long long p = pack_pv(pr[c], (unsigned)c);
        if (p > a0)      { a1 = a0; a0 = p; }
        else if (p > a1) { a1 = p; }
      }
    }
  }
  #pragma unroll
  for (int off = 1; off < 64; off <<= 1) {
    unsigned long long b0 = __shfl_xor(a0, off, 64);
    unsigned long long b1 = __shfl_xor(a1, off, 64);
    if (b0 > a0) { a1 = (a0 > b1) ? a0 : b1; a0 = b0; }
    else         { a1 = (b0 > a1) ? b0 : a1; }
  }
  const unsigned i0 = ~(unsigned)(a0 & 0xFFFFFFFFull);
  const unsigned i1 = ~(unsigned)(a1 & 0xFFFFFFFFull);

  // ---------------- Phase B: keys + straight copy out=x ----------------
  // Lane l owns channels k*256 + l*4 + m (k=0..15, m=0..3): perfectly coalesced float4.
  const float* xr   = x   + (size_t)row * Dn + l * 4;
  const float* w0   = W   + (size_t)i0  * Dn + l * 4;
  const float* w1   = W   + (size_t)i1  * Dn + l * 4;
  float*       orow = out + (size_t)row * Dn + l * 4;

  unsigned key[64];
  #pragma unroll
  for (int k = 0; k < 16; ++k) {
    float4 xx = *reinterpret_cast<const float4*>(xr + k * 256);
    float4 aa = *reinterpret_cast<const float4*>(w0 + k * 256);
    float4 bb = *reinterpret_cast<const float4*>(w1 + k * 256);
    key[k*4+0] = __float_as_uint(xx.x * (aa.x - bb.x)) & 0x7FFFFFFFu;
    key[k*4+1] = __float_as_uint(xx.y * (aa.y - bb.y)) & 0x7FFFFFFFu;
    key[k*4+2] = __float_as_uint(xx.z * (aa.z - bb.z)) & 0x7FFFFFFFu;
    key[k*4+3] = __float_as_uint(xx.w * (aa.w - bb.w)) & 0x7FFFFFFFu;
    *reinterpret_cast<float4*>(orow + k * 256) = xx;   // copy now, patch zeros later
  }

  // ---------------- Phase C: exact 1024th-largest key, 31-round wave-internal search ----------------
  unsigned cur = 0;
  #pragma unroll 1
  for (int bit = 30; bit >= 0; --bit) {
    const unsigned cand = cur | (1u << bit);
    unsigned cnt = 0;
    #pragma unroll
    for (int j = 0; j < 64; ++j)
      cnt += (unsigned)__popcll(__ballot(key[j] >= cand));
    if (cnt >= NDROP) cur = cand;
  }
  const unsigned V = cur;   // count(>V) < 1024 <= count(>=V)

  unsigned cnt_gt = 0, cnt_eq = 0;
  #pragma unroll
  for (int j = 0; j < 64; ++j) {
    cnt_gt += (unsigned)__popcll(__ballot(key[j] >  V));
    cnt_eq += (unsigned)__popcll(__ballot(key[j] == V));
  }
  const unsigned need_eq = NDROP - cnt_gt;   // 1 <= need_eq <= cnt_eq

  // ---------------- Phase D: drop mask (stable, lowest-channel-first ties) ----------------
  unsigned long long dropmask = 0ull;        // bit j => channel k*256+l*4+m dropped
  if (need_eq == cnt_eq) {
    #pragma unroll
    for (int j = 0; j < 64; ++j)
      if (key[j] >= V) dropmask |= (1ull << j);
  } else {
    // rare straddling tie: rank equal-key elements in increasing channel order
    unsigned base = 0;                       // eq elements in blocks k' < k
    #pragma unroll
    for (int k = 0; k < 16; ++k) {
      unsigned long long bm0 = __ballot(key[k*4+0] == V);
      unsigned long long bm1 = __ballot(key[k*4+1] == V);
      unsigned long long bm2 = __ballot(key[k*4+2] == V);
      unsigned long long bm3 = __ballot(key[k*4+3] == V);
      // within block k, channel order is lane-major: (l'*4 + m')
      unsigned beforeL = (unsigned)__popcll(bm0 & ltmask) + (unsigned)__popcll(bm1 & ltmask)
                       + (unsigned)__popcll(bm2 & ltmask) + (unsigned)__popcll(bm3 & ltmask);
      unsigned sameLane = 0;
      #pragma unroll
      for (int m = 0; m < 4; ++m) {
        const int j = k * 4 + m;
        if (key[j] == V) {
          unsigned rank = base + beforeL + sameLane;
          if (rank < need_eq) dropmask |= (1ull << j);
          ++sameLane;
        } else if (key[j] > V) {
          dropmask |= (1ull << j);
        }
      }
      base += (unsigned)__popcll(bm0) + (unsigned)__popcll(bm1)
            + (unsigned)__popcll(bm2) + (unsigned)__popcll(bm3);
    }
  }

  // ---------------- Phase E: patch zeros over dropped channels ----------------
  // Ensure the phase-B copy stores have committed before overwriting subsets of them.
  // (All phase-B traffic completed long ago during the ~4000-cycle search: this is free.)
  asm volatile("s_waitcnt vmcnt(0)" ::: "memory");
  #pragma unroll
  for (int k = 0; k < 16; ++k) {
    #pragma unroll
    for (int m = 0; m < 4; ++m) {
      if ((dropmask >> (k * 4 + m)) & 1ull)
        orow[k * 256 + m] = 0.0f;
    }
  }
}

extern "C" void kernel_launch(void* const* d_in, const int* in_sizes, int n_in,
                              void* d_out, int out_size, void* d_ws, size_t ws_size,
                              hipStream_t stream) {
  const float* x    = (const float*)d_in[0];
  const float* prev = (const float*)d_in[1];
  const float* W    = (const float*)d_in[2];
  float* out        = (float*)d_out;
  const int Brows   = in_sizes[0] / Dn;          // 16384
  ConfusionDropout_52407190946399_kernel<<<Brows / (TPB / 64), TPB, 0, stream>>>(x, prev, W, out);
}

// Round 3
// 543.283 us; speedup vs baseline: 1.2461x; 1.2461x over previous
//
#include <hip/hip_runtime.h>
#include <cstdint>
#include <cstddef>

// ConfusionDropout: B=16384 rows; D=4096 channels; C=1000 classes; drop top 25% (1024).
// Block per row (4 waves, 16 channels/thread). Loads explicitly staged for MLP;
// __launch_bounds__(256,4) raises the VGPR budget to 128 so staging stays in regs.
constexpr int Dn    = 4096;
constexpr int Cn    = 1000;
constexpr int NDROP = 1024;   // Dn * 0.25
constexpr int TPB   = 256;

// Monotonic (value, smaller-index-wins) packing matching lax.top_k tie-break.
__device__ __forceinline__ unsigned long long pack_pv(float v, unsigned idx) {
  unsigned b = __float_as_uint(v);
  unsigned u = b ^ ((b & 0x80000000u) ? 0xFFFFFFFFu : 0x80000000u);
  return ((unsigned long long)u << 32) | (unsigned)(~idx);
}

__global__ __launch_bounds__(TPB, 4) void ConfusionDropout_52407190946399_kernel(
    const float* __restrict__ x,
    const float* __restrict__ prev,
    const float* __restrict__ W,
    float* __restrict__ out)
{
  const int t    = threadIdx.x;
  const int wave = t >> 6;
  const int row  = blockIdx.x;

  __shared__ unsigned long long s_top[4][2];   // per-wave (a0,a1)
  __shared__ unsigned s_cnt[2][4];             // double-buffered per-wave counts
  __shared__ unsigned s_cnt2[2][4];            // gt / eq counts
  __shared__ unsigned s_scan[TPB];             // rare-path tie scan

  // -------- Stage independent loads FIRST: 4x x (float4) + 4x prev (scalar) --------
  const float* xr = x + (size_t)row * Dn + t * 16;
  const float4 xx0 = *reinterpret_cast<const float4*>(xr + 0);
  const float4 xx1 = *reinterpret_cast<const float4*>(xr + 4);
  const float4 xx2 = *reinterpret_cast<const float4*>(xr + 8);
  const float4 xx3 = *reinterpret_cast<const float4*>(xr + 12);

  const float* pr = prev + (size_t)row * Cn;
  float pv0 = 0.f, pv1 = 0.f, pv2 = 0.f, pv3 = 0.f;
  const bool g3 = (t + 768) < Cn;
  pv0 = pr[t];            // t < 1000 always (t<256)
  pv1 = pr[t + 256];
  pv2 = pr[t + 512];
  if (g3) pv3 = pr[t + 768];

  // ---------------- Phase A: top-2 of prev[row,:] (hides the x loads) ----------------
  unsigned long long a0 = 0ull, a1 = 0ull;
  {
    unsigned long long p;
    p = pack_pv(pv0, (unsigned)t);                    if (p > a0) { a1 = a0; a0 = p; } else if (p > a1) a1 = p;
    p = pack_pv(pv1, (unsigned)(t + 256));            if (p > a0) { a1 = a0; a0 = p; } else if (p > a1) a1 = p;
    p = pack_pv(pv2, (unsigned)(t + 512));            if (p > a0) { a1 = a0; a0 = p; } else if (p > a1) a1 = p;
    if (g3) { p = pack_pv(pv3, (unsigned)(t + 768));  if (p > a0) { a1 = a0; a0 = p; } else if (p > a1) a1 = p; }
  }
  #pragma unroll
  for (int off = 1; off < 64; off <<= 1) {
    unsigned long long b0 = __shfl_xor(a0, off, 64);
    unsigned long long b1 = __shfl_xor(a1, off, 64);
    if (b0 > a0) { a1 = (a0 > b1) ? a0 : b1; a0 = b0; }
    else         { a1 = (b0 > a1) ? b0 : a1; }
  }
  if ((t & 63) == 0) { s_top[wave][0] = a0; s_top[wave][1] = a1; }
  __syncthreads();
  {
    unsigned long long m0 = s_top[0][0], m1 = s_top[0][1];
    #pragma unroll
    for (int w = 1; w < 4; ++w) {
      unsigned long long b0 = s_top[w][0], b1 = s_top[w][1];
      if (b0 > m0) { m1 = (m0 > b1) ? m0 : b1; m0 = b0; }
      else         { m1 = (b0 > m1) ? b0 : m1; }
    }
    a0 = m0; a1 = m1;
  }
  const unsigned i0 = ~(unsigned)(a0 & 0xFFFFFFFFull);
  const unsigned i1 = ~(unsigned)(a1 & 0xFFFFFFFFull);

  // ---------------- Phase B: stage all 8 W loads, then compute keys ----------------
  const float* w0 = W + (size_t)i0 * Dn + t * 16;
  const float* w1 = W + (size_t)i1 * Dn + t * 16;
  const float4 aa0 = *reinterpret_cast<const float4*>(w0 + 0);
  const float4 aa1 = *reinterpret_cast<const float4*>(w0 + 4);
  const float4 aa2 = *reinterpret_cast<const float4*>(w0 + 8);
  const float4 aa3 = *reinterpret_cast<const float4*>(w0 + 12);
  const float4 bb0 = *reinterpret_cast<const float4*>(w1 + 0);
  const float4 bb1 = *reinterpret_cast<const float4*>(w1 + 4);
  const float4 bb2 = *reinterpret_cast<const float4*>(w1 + 8);
  const float4 bb3 = *reinterpret_cast<const float4*>(w1 + 12);

  unsigned key[16];
  key[ 0] = __float_as_uint(xx0.x * (aa0.x - bb0.x)) & 0x7FFFFFFFu;
  key[ 1] = __float_as_uint(xx0.y * (aa0.y - bb0.y)) & 0x7FFFFFFFu;
  key[ 2] = __float_as_uint(xx0.z * (aa0.z - bb0.z)) & 0x7FFFFFFFu;
  key[ 3] = __float_as_uint(xx0.w * (aa0.w - bb0.w)) & 0x7FFFFFFFu;
  key[ 4] = __float_as_uint(xx1.x * (aa1.x - bb1.x)) & 0x7FFFFFFFu;
  key[ 5] = __float_as_uint(xx1.y * (aa1.y - bb1.y)) & 0x7FFFFFFFu;
  key[ 6] = __float_as_uint(xx1.z * (aa1.z - bb1.z)) & 0x7FFFFFFFu;
  key[ 7] = __float_as_uint(xx1.w * (aa1.w - bb1.w)) & 0x7FFFFFFFu;
  key[ 8] = __float_as_uint(xx2.x * (aa2.x - bb2.x)) & 0x7FFFFFFFu;
  key[ 9] = __float_as_uint(xx2.y * (aa2.y - bb2.y)) & 0x7FFFFFFFu;
  key[10] = __float_as_uint(xx2.z * (aa2.z - bb2.z)) & 0x7FFFFFFFu;
  key[11] = __float_as_uint(xx2.w * (aa2.w - bb2.w)) & 0x7FFFFFFFu;
  key[12] = __float_as_uint(xx3.x * (aa3.x - bb3.x)) & 0x7FFFFFFFu;
  key[13] = __float_as_uint(xx3.y * (aa3.y - bb3.y)) & 0x7FFFFFFFu;
  key[14] = __float_as_uint(xx3.z * (aa3.z - bb3.z)) & 0x7FFFFFFFu;
  key[15] = __float_as_uint(xx3.w * (aa3.w - bb3.w)) & 0x7FFFFFFFu;

  // ---------------- Phase C: exact 1024th-largest key (31 block rounds) ----------------
  unsigned cur = 0;
  #pragma unroll 1
  for (int bit = 30; bit >= 0; --bit) {
    const unsigned cand = cur | (1u << bit);
    unsigned wc = 0;
    #pragma unroll
    for (int j = 0; j < 16; ++j)
      wc += (unsigned)__popcll(__ballot(key[j] >= cand));
    if ((t & 63) == 0) s_cnt[bit & 1][wave] = wc;
    __syncthreads();
    const unsigned tot = s_cnt[bit & 1][0] + s_cnt[bit & 1][1] +
                         s_cnt[bit & 1][2] + s_cnt[bit & 1][3];
    if (tot >= NDROP) cur = cand;
  }
  const unsigned V = cur;   // count(>V) < 1024 <= count(>=V)

  unsigned wgt = 0, weq = 0;
  #pragma unroll
  for (int j = 0; j < 16; ++j) {
    wgt += (unsigned)__popcll(__ballot(key[j] >  V));
    weq += (unsigned)__popcll(__ballot(key[j] == V));
  }
  if ((t & 63) == 0) { s_cnt2[0][wave] = wgt; s_cnt2[1][wave] = weq; }
  __syncthreads();
  const unsigned cnt_gt  = s_cnt2[0][0] + s_cnt2[0][1] + s_cnt2[0][2] + s_cnt2[0][3];
  const unsigned cnt_eq  = s_cnt2[1][0] + s_cnt2[1][1] + s_cnt2[1][2] + s_cnt2[1][3];
  const unsigned need_eq = NDROP - cnt_gt;   // 1 <= need_eq <= cnt_eq

  // ---------------- Phase D: drop mask (stable lowest-channel-first ties) ----------------
  bool drop[16];
  if (need_eq == cnt_eq) {
    #pragma unroll
    for (int j = 0; j < 16; ++j) drop[j] = (key[j] >= V);
  } else {
    unsigned c = 0;
    #pragma unroll
    for (int j = 0; j < 16; ++j) c += (key[j] == V) ? 1u : 0u;
    s_scan[t] = c;
    __syncthreads();
    for (int off = 1; off < TPB; off <<= 1) {
      unsigned add = (t >= off) ? s_scan[t - off] : 0u;
      __syncthreads();
      s_scan[t] += add;
      __syncthreads();
    }
    unsigned run = s_scan[t] - c;   // exclusive prefix of eq-count in channel order
    #pragma unroll
    for (int j = 0; j < 16; ++j) {
      if (key[j] == V) { drop[j] = (run < need_eq); ++run; }
      else             { drop[j] = (key[j] > V); }
    }
  }

  // ---------------- Phase E: single masked store from registers ----------------
  float* orow = out + (size_t)row * Dn + t * 16;
  float4 o0 = xx0, o1 = xx1, o2 = xx2, o3 = xx3;
  if (drop[ 0]) o0.x = 0.0f;  if (drop[ 1]) o0.y = 0.0f;
  if (drop[ 2]) o0.z = 0.0f;  if (drop[ 3]) o0.w = 0.0f;
  if (drop[ 4]) o1.x = 0.0f;  if (drop[ 5]) o1.y = 0.0f;
  if (drop[ 6]) o1.z = 0.0f;  if (drop[ 7]) o1.w = 0.0f;
  if (drop[ 8]) o2.x = 0.0f;  if (drop[ 9]) o2.y = 0.0f;
  if (drop[10]) o2.z = 0.0f;  if (drop[11]) o2.w = 0.0f;
  if (drop[12]) o3.x = 0.0f;  if (drop[13]) o3.y = 0.0f;
  if (drop[14]) o3.z = 0.0f;  if (drop[15]) o3.w = 0.0f;
  *reinterpret_cast<float4*>(orow + 0)  = o0;
  *reinterpret_cast<float4*>(orow + 4)  = o1;
  *reinterpret_cast<float4*>(orow + 8)  = o2;
  *reinterpret_cast<float4*>(orow + 12) = o3;
}

extern "C" void kernel_launch(void* const* d_in, const int* in_sizes, int n_in,
                              void* d_out, int out_size, void* d_ws, size_t ws_size,
                              hipStream_t stream) {
  const float* x    = (const float*)d_in[0];
  const float* prev = (const float*)d_in[1];
  const float* W    = (const float*)d_in[2];
  float* out        = (float*)d_out;
  const int Brows   = in_sizes[0] / Dn;   // 16384
  ConfusionDropout_52407190946399_kernel<<<Brows, TPB, 0, stream>>>(x, prev, W, out);
}